// Round 4
// baseline (198.739 us; speedup 1.0000x reference)
//
#include <hip/hip_runtime.h>
#include <stdint.h>

#define NBOX 8000
#define NPAD 8192
#define CAPE 512                             // per-bucket edge capacity
#define ELDSCAP 6144                         // packed-edge LDS capacity

// ---- workspace layout (bytes) ----
#define DONE_OFF 64                          // u32 finished-block count (zeroed by K1)
#define BCNT_OFF 0x100                       // 128 x u32 per-j-chunk edge counts (zeroed by K1)
#define SB(i)    (0x10000 + (size_t)(i) * 0x8000)
// sorted-by-rank arrays (float[8192] each):
// 0 bx, 1 by, 2 bw, 3 bh, 4 conf, 5 cls, 6 x1, 7 y1, 8 x2, 9 y2, 10 area
#define EDGE_OFF  (size_t)0x200000           // 128 buckets x CAPE u32 edges (i<<13|j)
#define INTRA_OFF (size_t)0x240000           // 128 chunks x 64 u64 intra-chunk rows (zeroed by K1)

__device__ __forceinline__ float sigmoidf_(float x) {
    return 1.0f / (1.0f + expf(-x));
}

// ================= K1: fused decode-conf + ballot-rank + scatter-to-sorted =================
// (verified rounds 1-3; only change: zeroes DONE/BCNT/INTRA instead of ECNT)
__global__ __launch_bounds__(512) void sort_decode_kernel(const float* __restrict__ x,
                                                          const float* __restrict__ anchors,
                                                          unsigned char* __restrict__ ws) {
    __shared__ unsigned long long keys[NPAD];    // 64 KB
    __shared__ int partial[256];                 // 8 waves x 32 rows
    int tid  = threadIdx.x;
    int lane = tid & 63;
    int wv   = tid >> 6;                         // wave 0..7
    int b    = blockIdx.x;                       // 256 blocks

    if (b == 0) {
        if (tid == 0) *(unsigned int*)(ws + DONE_OFF) = 0u;
        if (tid < 128) ((unsigned int*)(ws + BCNT_OFF))[tid] = 0u;
    }
    if (tid < 32)                                // 256 blocks x 32 u64 = 64 KB intra matrix
        ((unsigned long long*)(ws + INTRA_OFF))[(b << 5) + tid] = 0ull;

    // ---- phase 1: all keys -> LDS (16 coalesced loads/thread) ----
    for (int t = tid; t < NPAD; t += 512) {
        unsigned long long k;
        if (t < NBOX) {
            int a = t / 1600, pos = t - a * 1600;
            float c = sigmoidf_(x[a * 40000 + 4 * 1600 + pos]);
            k = ((unsigned long long)__float_as_uint(c) << 32) | (unsigned long long)(8191 - t);
        } else {
            k = (unsigned long long)(8191 - t);  // pads sort last (conf bits = 0)
        }
        keys[t] = k;
    }
    __syncthreads();

    // ---- phase 2: ballot-rank; wave wv vs segment wv ----
    unsigned long long kj[16];
    #pragma unroll
    for (int c = 0; c < 16; ++c) kj[c] = keys[(wv << 10) + (c << 6) + lane];
    unsigned long long ki = keys[(b << 5) + lane];

    int vout = 0;                                // lane L ends with partial for row L
    for (int ii = 0; ii < 32; ++ii) {
        unsigned int klo = (unsigned int)__builtin_amdgcn_readlane((int)(unsigned int)ki, ii);
        unsigned int khi = (unsigned int)__builtin_amdgcn_readlane((int)(unsigned int)(ki >> 32), ii);
        unsigned long long kib = ((unsigned long long)khi << 32) | (unsigned long long)klo;
        int c = 0;
        #pragma unroll
        for (int ch = 0; ch < 16; ++ch)
            c += __popcll(__ballot(kj[ch] > kib));
        vout = (lane == ii) ? c : vout;
    }
    if (lane < 32) partial[(wv << 5) + lane] = vout;
    __syncthreads();

    // ---- phase 3: wave 0 lanes 0..31 sum partials, decode, scatter-write ----
    if (wv == 0 && lane < 32) {
        int r = 0;
        #pragma unroll
        for (int s = 0; s < 8; ++s) r += partial[(s << 5) + lane];

        int i = (b << 5) + lane;                 // source box owned by this lane
        float bx = 0.f, by = 0.f, bw = 0.f, bh = 0.f, conf = 0.f, cls = -1.0f;
        if (i < NBOX) {                          // full decode (coalesced channel loads)
            int a = i / 1600, pos = i - a * 1600;
            int gy = pos / 40, gx = pos - gy * 40;
            const float* p = x + (size_t)a * 40000 + pos;
            float tx = sigmoidf_(p[0]);
            float ty = sigmoidf_(p[1600]);
            float tw = p[2 * 1600];
            float th = p[3 * 1600];
            conf = sigmoidf_(p[4 * 1600]);
            float best = -1.0f; int bi = 0;
            #pragma unroll
            for (int c = 0; c < 20; ++c) {       // first-max wins, matches jnp.argmax
                float v = sigmoidf_(p[(5 + c) * 1600]);
                if (v > best) { best = v; bi = c; }
            }
            float aw = anchors[a * 2 + 0];
            float ah = anchors[a * 2 + 1];
            bx = (tx + (float)gx) * 8.0f;
            by = (ty + (float)gy) * 8.0f;
            bw = expf(tw) * aw * 8.0f;
            bh = expf(th) * ah * 8.0f;
            cls = (float)bi;
        }
        {
        #pragma clang fp contract(off)
            float x1 = bx - bw / 2.0f, y1 = by - bh / 2.0f;
            float x2 = bx + bw / 2.0f, y2 = by + bh / 2.0f;
            float ar = fabsf((x2 - x1) * (y2 - y1));   // ref: recomputed from corners
            ((float*)(ws + SB(0)))[r]  = bx;  ((float*)(ws + SB(1)))[r]  = by;
            ((float*)(ws + SB(2)))[r]  = bw;  ((float*)(ws + SB(3)))[r]  = bh;
            ((float*)(ws + SB(4)))[r]  = conf; ((float*)(ws + SB(5)))[r] = cls;
            ((float*)(ws + SB(6)))[r]  = x1;  ((float*)(ws + SB(7)))[r]  = y1;
            ((float*)(ws + SB(8)))[r]  = x2;  ((float*)(ws + SB(9)))[r]  = y2;
            ((float*)(ws + SB(10)))[r] = ar;
        }
    }
}

// ================= K2: suppression edges + last-block chunked-greedy NMS + output =================
// Phase 1 (grid): verified tile loop; edges now bucketed by j-chunk (cross)
// or OR'd into a 64x64 intra-chunk bit matrix (same-chunk).
// Tail (last block via done-counter): stage edges+matrix in LDS, then ONE
// wave sweeps the 128 rank-chunks in order — cross-edge suppression uses
// only FINALIZED alive bits (i < chunk base), intra-chunk bits resolved by
// an ascending scan over matrix rows. Exact greedy in O(V/64) steps instead
// of O(chain-depth) Jacobi passes. Output phase unchanged (verified).
__global__ __launch_bounds__(512) void mask_nms_out_kernel(unsigned char* __restrict__ ws,
                                                           float* __restrict__ out) {
    __shared__ unsigned long long av[128];                // final alive bits
    __shared__ union {
        struct { float cst[2][7][64]; } m;                // 3.5 KB mask staging
        struct { unsigned int offs[128], cntL[128];
                 unsigned long long vd[128];
                 unsigned int eLDS[ELDSCAP];
                 unsigned long long intra[128 * 64]; } r; // ~92 KB resolve staging
        struct { float obuf[2][3072]; } o;                // 24 KB output staging
    } u;
    __shared__ int lastBlk;

    int tid  = threadIdx.x;
    int lane = tid & 63;
    int wv   = tid >> 6;
    int blk  = blockIdx.x;                                // 256 blocks

    const float* sconf = (const float*)(ws + SB(4));
    const float* sx1 = (const float*)(ws + SB(6));
    const float* sy1 = (const float*)(ws + SB(7));
    const float* sx2 = (const float*)(ws + SB(8));
    const float* sy2 = (const float*)(ws + SB(9));
    const float* sar = (const float*)(ws + SB(10));
    const float* scl = (const float*)(ws + SB(5));

    // ---------------- phase 1: suppression-edge tiles (verified loop) ----------------
    {
    #pragma clang fp contract(off)
        int h  = tid >> 8;                       // half-block 0/1 (4 waves each)
        int tl = tid & 255;

        for (int k = 0; k < 8; ++k) {
            int t  = k * 512 + (blk << 1) + h;   // tile id in [0, 4096)
            int iy = t >> 7, w = t & 127;
            int i0 = iy << 8, j0 = w << 6;
            bool skip = (sconf[i0] <= 0.5f) || (sconf[j0] <= 0.5f) || (j0 + 64 <= i0);

            if (!skip && tl < 64) {
                int j = j0 + tl;
                u.m.cst[h][0][tl] = sx1[j]; u.m.cst[h][1][tl] = sy1[j];
                u.m.cst[h][2][tl] = sx2[j]; u.m.cst[h][3][tl] = sy2[j];
                u.m.cst[h][4][tl] = sar[j]; u.m.cst[h][5][tl] = scl[j];
                u.m.cst[h][6][tl] = sconf[j];
            }
            __syncthreads();

            if (!skip) {
                int i = i0 + tl;
                unsigned long long word = 0;
                if (sconf[i] > 0.5f && j0 + 64 > i + 1) {  // row i valid
                    float x1i = sx1[i], y1i = sy1[i], x2i = sx2[i], y2i = sy2[i];
                    float ai = sar[i], ci = scl[i];
                    for (int jj = 0; jj < 64; ++jj) {
                        int j = j0 + jj;
                        if (j <= i) continue;
                        if (u.m.cst[h][6][jj] <= 0.5f) continue;   // col j invalid
                        if (u.m.cst[h][5][jj] != ci) continue;     // class mismatch
                        float iw = fminf(x2i, u.m.cst[h][2][jj]) - fmaxf(x1i, u.m.cst[h][0][jj]);
                        iw = fmaxf(iw, 0.0f);
                        float ih = fminf(y2i, u.m.cst[h][3][jj]) - fmaxf(y1i, u.m.cst[h][1][jj]);
                        ih = fmaxf(ih, 0.0f);
                        float inter = iw * ih;
                        float denom = ai + u.m.cst[h][4][jj] - inter + 1e-6f;
                        if (inter / denom >= 0.5f) word |= (1ull << jj);
                    }
                }
                // emit: bucket by j-chunk (cross) / intra matrix (same chunk)
                unsigned long long tw = word;
                while (tw) {
                    int bit = __builtin_ctzll(tw);
                    tw &= tw - 1ull;
                    unsigned int j  = (unsigned int)(j0 + bit);
                    unsigned int jc = j >> 6;
                    if (jc == ((unsigned int)i >> 6)) {
                        atomicOr((unsigned long long*)(ws + INTRA_OFF) + (jc << 6) + (i & 63),
                                 1ull << (j & 63));
                    } else {
                        unsigned int idx = atomicAdd((unsigned int*)(ws + BCNT_OFF) + jc, 1u);
                        if (idx < CAPE)
                            ((unsigned int*)(ws + EDGE_OFF))[jc * CAPE + idx] =
                                ((unsigned int)i << 13) | j;
                    }
                }
            }
            __syncthreads();
        }
    }

    // ---------------- completion detection: last block continues ----------------
    __threadfence();                              // release this block's edge writes
    if (tid == 0)
        lastBlk = (atomicAdd((unsigned int*)(ws + DONE_OFF), 1u) == 255u);
    __syncthreads();
    if (!lastBlk) return;
    __threadfence();                              // acquire: see all blocks' edges

    // ---------------- tail step 1: valid bitmap + bucket offsets ----------------
    for (int c = wv; c < 128; c += 8) {
        unsigned long long mk = __ballot(sconf[(c << 6) + lane] > 0.5f);
        if (lane == 0) u.r.vd[c] = mk;
    }
    if (wv == 0) {                                // wave 0: clamp counts + prefix scan
        const unsigned int* bcntG = (const unsigned int*)(ws + BCNT_OFF);
        unsigned int a0 = min(bcntG[2 * lane + 0], (unsigned int)CAPE);
        unsigned int a1 = min(bcntG[2 * lane + 1], (unsigned int)CAPE);
        unsigned int s = a0 + a1, incl = s;
        #pragma unroll
        for (int d = 1; d < 64; d <<= 1) {
            unsigned int t = __shfl_up(incl, d, 64);
            if (lane >= d) incl += t;
        }
        unsigned int excl = incl - s;
        u.r.offs[2 * lane + 0] = excl;       u.r.offs[2 * lane + 1] = excl + a0;
        u.r.cntL[2 * lane + 0] = a0;         u.r.cntL[2 * lane + 1] = a1;
    }
    __syncthreads();

    // ---------------- tail step 2: stage edges + intra matrix in LDS ----------------
    {
        const unsigned int* bucketG = (const unsigned int*)(ws + EDGE_OFF);
        for (int bkt = wv; bkt < 128; bkt += 8) {
            unsigned int cnt = u.r.cntL[bkt], off = u.r.offs[bkt];
            for (unsigned int e = lane; e < cnt; e += 64) {
                unsigned int dst = off + e;
                if (dst < (unsigned int)ELDSCAP) u.r.eLDS[dst] = bucketG[bkt * CAPE + e];
            }
        }
        const unsigned long long* intraG = (const unsigned long long*)(ws + INTRA_OFF);
        for (int t = tid; t < 128 * 64; t += 512) u.r.intra[t] = intraG[t];
    }
    __syncthreads();

    // ---------------- tail step 3: chunked greedy resolve (wave 0 only) ----------------
    if (wv == 0) {
        for (int jc = 0; jc < 128; ++jc) {
            unsigned long long v = u.r.vd[jc];
            if (v == 0ull) { if (lane == 0) av[jc] = 0ull; continue; }
            // cross-chunk suppression: i < jc*64 => alive[i] is FINAL
            unsigned int cnt = u.r.cntL[jc], off = u.r.offs[jc];
            unsigned long long m = 0ull;
            for (unsigned int e0 = 0; e0 < cnt; e0 += 64) {
                unsigned int e = e0 + lane;
                unsigned long long mm = 0ull;
                if (e < cnt && off + e < (unsigned int)ELDSCAP) {
                    unsigned int uu = u.r.eLDS[off + e];
                    unsigned int i = uu >> 13, j = uu & 8191u;
                    if ((av[i >> 6] >> (i & 63)) & 1ull) mm = 1ull << (j & 63);
                }
                m |= mm;
            }
            #pragma unroll
            for (int d = 1; d < 64; d <<= 1) m |= __shfl_xor((unsigned long long)m, d, 64);
            unsigned long long a = v & ~m;
            // intra-chunk: ascending scan over nonzero matrix rows (j bits > i only)
            unsigned long long myrow = u.r.intra[(jc << 6) + lane];
            unsigned long long nz = __ballot(myrow != 0ull);
            unsigned long long pend = a & nz;
            while (pend) {
                int ib = __builtin_ctzll(pend);
                pend &= pend - 1ull;
                if ((a >> ib) & 1ull) a &= ~u.r.intra[(jc << 6) + ib];
            }
            if (lane == 0) av[jc] = a;
        }
    }
    __syncthreads();

    // ---------------- tail step 4: output (verified 16-chunk LDS transpose) ----------------
    {
        const float* s0 = (const float*)(ws + SB(0));
        const float* s1 = (const float*)(ws + SB(1));
        const float* s2 = (const float*)(ws + SB(2));
        const float* s3 = (const float*)(ws + SB(3));
        const float* s4 = (const float*)(ws + SB(4));
        const float* s5 = (const float*)(ws + SB(5));

        for (int c = 0; c < 16; ++c) {
            int r = (c << 9) + tid;               // rank 0..8191
            int p = c & 1;
            float v0 = 0.f, v1 = 0.f, v2 = 0.f, v3 = 0.f, v4 = 0.f, v5 = 0.f;
            if ((av[r >> 6] >> (r & 63)) & 1ull) {
                v0 = s0[r]; v1 = s1[r]; v2 = s2[r];
                v3 = s3[r]; v4 = s4[r]; v5 = s5[r];
            }
            u.o.obuf[p][tid * 6 + 0] = v0; u.o.obuf[p][tid * 6 + 1] = v1;
            u.o.obuf[p][tid * 6 + 2] = v2; u.o.obuf[p][tid * 6 + 3] = v3;
            u.o.obuf[p][tid * 6 + 4] = v4; u.o.obuf[p][tid * 6 + 5] = v5;
            __syncthreads();
            int basef = c * 3072;                 // float index of chunk start
            const float4* src = (const float4*)u.o.obuf[p];
            float4* dst = (float4*)(out + basef);
            #pragma unroll
            for (int tq = tid; tq < 768; tq += 512)
                if ((basef >> 2) + tq < (NBOX * 6) / 4) dst[tq] = src[tq];
        }
    }
}

extern "C" void kernel_launch(void* const* d_in, const int* in_sizes, int n_in,
                              void* d_out, int out_size, void* d_ws, size_t ws_size,
                              hipStream_t stream) {
    const float* x       = (const float*)d_in[0];
    const float* anchors = (const float*)d_in[1];
    float* out           = (float*)d_out;
    unsigned char* ws    = (unsigned char*)d_ws;

    sort_decode_kernel<<<256, 512, 0, stream>>>(x, anchors, ws);
    mask_nms_out_kernel<<<256, 512, 0, stream>>>(ws, out);
}

// Round 5
// 194.601 us; speedup vs baseline: 1.0213x; 1.0213x over previous
//
#include <hip/hip_runtime.h>
#include <stdint.h>

#define NBOX 8000
#define NPAD 8192
#define ECAP 6144                            // packed cross-edge LDS capacity

// ---- workspace layout (bytes) ----
#define ECNT_OFF 0                           // u32 edge count (zeroed by K1)
#define DONE_OFF 64                          // u32 finished-block count (zeroed by K1)
#define SB(i)    (0x10000 + (size_t)(i) * 0x8000)
// sorted-by-rank arrays (float[8192] each):
// 0 bx, 1 by, 2 bw, 3 bh, 4 conf, 5 cls, 6 x1, 7 y1, 8 x2, 9 y2, 10 area
#define EDGE_OFF (size_t)0x200000            // flat u32 edges (i<<13|j)

__device__ __forceinline__ float sigmoidf_(float x) {
    return 1.0f / (1.0f + expf(-x));
}

// ================= K1: fused decode-conf + ballot-rank + scatter-to-sorted =================
// (verbatim verified rounds 1-3)
__global__ __launch_bounds__(512) void sort_decode_kernel(const float* __restrict__ x,
                                                          const float* __restrict__ anchors,
                                                          unsigned char* __restrict__ ws) {
    __shared__ unsigned long long keys[NPAD];    // 64 KB
    __shared__ int partial[256];                 // 8 waves x 32 rows
    int tid  = threadIdx.x;
    int lane = tid & 63;
    int wv   = tid >> 6;                         // wave 0..7
    int b    = blockIdx.x;                       // 256 blocks

    if (b == 0 && tid == 0) {
        *(unsigned int*)(ws + ECNT_OFF) = 0u;    // edge count for K2
        *(unsigned int*)(ws + DONE_OFF) = 0u;    // done-block count for K2
    }

    // ---- phase 1: all keys -> LDS (16 coalesced loads/thread) ----
    for (int t = tid; t < NPAD; t += 512) {
        unsigned long long k;
        if (t < NBOX) {
            int a = t / 1600, pos = t - a * 1600;
            float c = sigmoidf_(x[a * 40000 + 4 * 1600 + pos]);
            k = ((unsigned long long)__float_as_uint(c) << 32) | (unsigned long long)(8191 - t);
        } else {
            k = (unsigned long long)(8191 - t);  // pads sort last (conf bits = 0)
        }
        keys[t] = k;
    }
    __syncthreads();

    // ---- phase 2: ballot-rank; wave wv vs segment wv ----
    unsigned long long kj[16];
    #pragma unroll
    for (int c = 0; c < 16; ++c) kj[c] = keys[(wv << 10) + (c << 6) + lane];
    unsigned long long ki = keys[(b << 5) + lane];

    int vout = 0;                                // lane L ends with partial for row L
    for (int ii = 0; ii < 32; ++ii) {
        unsigned int klo = (unsigned int)__builtin_amdgcn_readlane((int)(unsigned int)ki, ii);
        unsigned int khi = (unsigned int)__builtin_amdgcn_readlane((int)(unsigned int)(ki >> 32), ii);
        unsigned long long kib = ((unsigned long long)khi << 32) | (unsigned long long)klo;
        int c = 0;
        #pragma unroll
        for (int ch = 0; ch < 16; ++ch)
            c += __popcll(__ballot(kj[ch] > kib));
        vout = (lane == ii) ? c : vout;
    }
    if (lane < 32) partial[(wv << 5) + lane] = vout;
    __syncthreads();

    // ---- phase 3: wave 0 lanes 0..31 sum partials, decode, scatter-write ----
    if (wv == 0 && lane < 32) {
        int r = 0;
        #pragma unroll
        for (int s = 0; s < 8; ++s) r += partial[(s << 5) + lane];

        int i = (b << 5) + lane;                 // source box owned by this lane
        float bx = 0.f, by = 0.f, bw = 0.f, bh = 0.f, conf = 0.f, cls = -1.0f;
        if (i < NBOX) {                          // full decode (coalesced channel loads)
            int a = i / 1600, pos = i - a * 1600;
            int gy = pos / 40, gx = pos - gy * 40;
            const float* p = x + (size_t)a * 40000 + pos;
            float tx = sigmoidf_(p[0]);
            float ty = sigmoidf_(p[1600]);
            float tw = p[2 * 1600];
            float th = p[3 * 1600];
            conf = sigmoidf_(p[4 * 1600]);
            float best = -1.0f; int bi = 0;
            #pragma unroll
            for (int c = 0; c < 20; ++c) {       // first-max wins, matches jnp.argmax
                float v = sigmoidf_(p[(5 + c) * 1600]);
                if (v > best) { best = v; bi = c; }
            }
            float aw = anchors[a * 2 + 0];
            float ah = anchors[a * 2 + 1];
            bx = (tx + (float)gx) * 8.0f;
            by = (ty + (float)gy) * 8.0f;
            bw = expf(tw) * aw * 8.0f;
            bh = expf(th) * ah * 8.0f;
            cls = (float)bi;
        }
        {
        #pragma clang fp contract(off)
            float x1 = bx - bw / 2.0f, y1 = by - bh / 2.0f;
            float x2 = bx + bw / 2.0f, y2 = by + bh / 2.0f;
            float ar = fabsf((x2 - x1) * (y2 - y1));   // ref: recomputed from corners
            ((float*)(ws + SB(0)))[r]  = bx;  ((float*)(ws + SB(1)))[r]  = by;
            ((float*)(ws + SB(2)))[r]  = bw;  ((float*)(ws + SB(3)))[r]  = bh;
            ((float*)(ws + SB(4)))[r]  = conf; ((float*)(ws + SB(5)))[r] = cls;
            ((float*)(ws + SB(6)))[r]  = x1;  ((float*)(ws + SB(7)))[r]  = y1;
            ((float*)(ws + SB(8)))[r]  = x2;  ((float*)(ws + SB(9)))[r]  = y2;
            ((float*)(ws + SB(10)))[r] = ar;
        }
    }
}

// ================= K2: suppression edges + last-block chunked-greedy NMS + output =================
// Phase 1 (grid): round-3 verified tile loop with wave-aggregated flat-edge
// emission (ONE device atomic per wave; fire-and-forget stores — no dependent
// per-edge atomic chains, which caused round-4's regression).
// Tail (last block via done-counter): bucket the flat edge list by j-chunk
// IN LDS (LDS atomics), build the 64x64 intra-chunk bit matrix in LDS, then
// one wave sweeps the 128 rank-chunks in order (exact greedy, round-4
// verified resolve). Jacobi fallback if E overflows LDS (never on this data).
__global__ __launch_bounds__(512) void mask_nms_out_kernel(unsigned char* __restrict__ ws,
                                                           float* __restrict__ out) {
    __shared__ unsigned long long av[128];                // final alive bits
    __shared__ union {
        struct { float cst[2][7][64]; } m;                // 3.5 KB mask staging
        struct { unsigned int bcnt[128], offs[128], cur[128], cntL[128];
                 unsigned long long vd[128], supp[128];
                 unsigned int eLDS[ECAP];                 // 24 KB
                 unsigned long long intra[128 * 64]; } r; // 64 KB  => ~92 KB total
        struct { float obuf[2][3072]; } o;                // 24 KB output staging
    } u;
    __shared__ int lastBlk, flag;

    int tid  = threadIdx.x;
    int lane = tid & 63;
    int wv   = tid >> 6;
    int blk  = blockIdx.x;                                // 256 blocks

    const float* sconf = (const float*)(ws + SB(4));
    const float* sx1 = (const float*)(ws + SB(6));
    const float* sy1 = (const float*)(ws + SB(7));
    const float* sx2 = (const float*)(ws + SB(8));
    const float* sy2 = (const float*)(ws + SB(9));
    const float* sar = (const float*)(ws + SB(10));
    const float* scl = (const float*)(ws + SB(5));

    // ---------------- phase 1: suppression-edge tiles (round-3 verified) ----------------
    {
    #pragma clang fp contract(off)
        int h  = tid >> 8;                       // half-block 0/1 (4 waves each)
        int tl = tid & 255;

        for (int k = 0; k < 8; ++k) {
            int t  = k * 512 + (blk << 1) + h;   // tile id in [0, 4096)
            int iy = t >> 7, w = t & 127;
            int i0 = iy << 8, j0 = w << 6;
            bool skip = (sconf[i0] <= 0.5f) || (sconf[j0] <= 0.5f) || (j0 + 64 <= i0);

            if (!skip && tl < 64) {
                int j = j0 + tl;
                u.m.cst[h][0][tl] = sx1[j]; u.m.cst[h][1][tl] = sy1[j];
                u.m.cst[h][2][tl] = sx2[j]; u.m.cst[h][3][tl] = sy2[j];
                u.m.cst[h][4][tl] = sar[j]; u.m.cst[h][5][tl] = scl[j];
                u.m.cst[h][6][tl] = sconf[j];
            }
            __syncthreads();

            if (!skip) {
                int i = i0 + tl;
                unsigned long long word = 0;
                if (sconf[i] > 0.5f && j0 + 64 > i + 1) {  // row i valid
                    float x1i = sx1[i], y1i = sy1[i], x2i = sx2[i], y2i = sy2[i];
                    float ai = sar[i], ci = scl[i];
                    for (int jj = 0; jj < 64; ++jj) {
                        int j = j0 + jj;
                        if (j <= i) continue;
                        if (u.m.cst[h][6][jj] <= 0.5f) continue;   // col j invalid
                        if (u.m.cst[h][5][jj] != ci) continue;     // class mismatch
                        float iw = fminf(x2i, u.m.cst[h][2][jj]) - fmaxf(x1i, u.m.cst[h][0][jj]);
                        iw = fmaxf(iw, 0.0f);
                        float ih = fminf(y2i, u.m.cst[h][3][jj]) - fmaxf(y1i, u.m.cst[h][1][jj]);
                        ih = fmaxf(ih, 0.0f);
                        float inter = iw * ih;
                        float denom = ai + u.m.cst[h][4][jj] - inter + 1e-6f;
                        if (inter / denom >= 0.5f) word |= (1ull << jj);
                    }
                }
                // wave-aggregated edge emission (all 64 lanes of the wave)
                int pc = __popcll(word);
                int scan = pc;
                #pragma unroll
                for (int d = 1; d < 64; d <<= 1) {
                    int tt = __shfl_up(scan, d, 64);
                    if (lane >= d) scan += tt;
                }
                int total = __shfl(scan, 63, 64);
                if (total > 0) {
                    unsigned int base = 0;
                    if (lane == 63)
                        base = atomicAdd((unsigned int*)(ws + ECNT_OFF), (unsigned int)total);
                    base = (unsigned int)__shfl((int)base, 63, 64);
                    unsigned int off = base + (unsigned int)(scan - pc);   // exclusive prefix
                    unsigned int* edges = (unsigned int*)(ws + EDGE_OFF);
                    unsigned long long tw = word;
                    while (tw) {
                        int bit = __builtin_ctzll(tw);
                        tw &= tw - 1ull;
                        edges[off++] = ((unsigned int)i << 13) | (unsigned int)(j0 + bit);
                    }
                }
            }
            __syncthreads();
        }
    }

    // ---------------- completion detection: last block continues ----------------
    __threadfence();                              // release this block's edge writes
    if (tid == 0)
        lastBlk = (atomicAdd((unsigned int*)(ws + DONE_OFF), 1u) == 255u);
    __syncthreads();
    if (!lastBlk) return;
    __threadfence();                              // acquire: see all blocks' edges

    unsigned int E = *(const unsigned int*)(ws + ECNT_OFF);
    const unsigned int* edges = (const unsigned int*)(ws + EDGE_OFF);

    // ---------------- tail step 1: valid bitmap + zero LDS bucket state ----------------
    for (int c = wv; c < 128; c += 8) {
        unsigned long long mk = __ballot(sconf[(c << 6) + lane] > 0.5f);
        if (lane == 0) u.r.vd[c] = mk;
    }
    for (int t = tid; t < 128 * 64; t += 512) u.r.intra[t] = 0ull;
    if (tid < 128) u.r.bcnt[tid] = 0u;
    __syncthreads();

    if (E <= (unsigned int)ECAP) {
        // ---- pass 1: classify edges; count cross per j-chunk, OR intra bits ----
        for (unsigned int e = tid; e < E; e += 512) {
            unsigned int uu = edges[e];
            unsigned int i = uu >> 13, j = uu & 8191u;
            unsigned int jc = j >> 6;
            if ((i >> 6) == jc)
                atomicOr(&u.r.intra[(jc << 6) + (i & 63)], 1ull << (j & 63));
            else
                atomicAdd(&u.r.bcnt[jc], 1u);
        }
        __syncthreads();
        // ---- scan: exclusive prefix over 128 bucket counts (wave 0) ----
        if (wv == 0) {
            unsigned int a0 = u.r.bcnt[2 * lane + 0];
            unsigned int a1 = u.r.bcnt[2 * lane + 1];
            unsigned int s = a0 + a1, incl = s;
            #pragma unroll
            for (int d = 1; d < 64; d <<= 1) {
                unsigned int t = __shfl_up(incl, d, 64);
                if (lane >= d) incl += t;
            }
            unsigned int excl = incl - s;
            u.r.offs[2 * lane + 0] = excl;       u.r.offs[2 * lane + 1] = excl + a0;
            u.r.cur[2 * lane + 0]  = excl;       u.r.cur[2 * lane + 1]  = excl + a0;
            u.r.cntL[2 * lane + 0] = a0;         u.r.cntL[2 * lane + 1] = a1;
        }
        __syncthreads();
        // ---- pass 2: scatter cross edges into packed per-chunk lists (LDS atomics) ----
        for (unsigned int e = tid; e < E; e += 512) {
            unsigned int uu = edges[e];
            unsigned int i = uu >> 13, j = uu & 8191u;
            unsigned int jc = j >> 6;
            if ((i >> 6) != jc) {
                unsigned int idx = atomicAdd(&u.r.cur[jc], 1u);
                u.r.eLDS[idx] = uu;
            }
        }
        __syncthreads();
        // ---- resolve: chunked greedy sweep, wave 0 only (round-4 verified) ----
        if (wv == 0) {
            for (int jc = 0; jc < 128; ++jc) {
                unsigned long long v = u.r.vd[jc];
                if (v == 0ull) { if (lane == 0) av[jc] = 0ull; continue; }
                // cross-chunk suppression: i < jc*64 => alive[i] is FINAL
                unsigned int cnt = u.r.cntL[jc], off = u.r.offs[jc];
                unsigned long long m = 0ull;
                for (unsigned int e0 = 0; e0 < cnt; e0 += 64) {
                    unsigned int e = e0 + lane;
                    unsigned long long mm = 0ull;
                    if (e < cnt) {
                        unsigned int uu = u.r.eLDS[off + e];
                        unsigned int i = uu >> 13, j = uu & 8191u;
                        if ((av[i >> 6] >> (i & 63)) & 1ull) mm = 1ull << (j & 63);
                    }
                    m |= mm;
                }
                #pragma unroll
                for (int d = 1; d < 64; d <<= 1) m |= __shfl_xor((unsigned long long)m, d, 64);
                unsigned long long a = v & ~m;
                // intra-chunk: ascending scan over nonzero matrix rows (bits j>i only)
                unsigned long long myrow = u.r.intra[(jc << 6) + lane];
                unsigned long long nz = __ballot(myrow != 0ull);
                unsigned long long pend = a & nz;
                while (pend) {
                    int ib = __builtin_ctzll(pend);
                    pend &= pend - 1ull;
                    if ((a >> ib) & 1ull) a &= ~u.r.intra[(jc << 6) + ib];
                }
                if (lane == 0) av[jc] = a;
            }
        }
        __syncthreads();
    } else {
        // ---- fallback: Jacobi fixed point on global edges (round-3 verified; E>ECAP only) ----
        if (tid < 128) av[tid] = u.r.vd[tid];
        __syncthreads();
        for (;;) {
            if (tid < 128) u.r.supp[tid] = 0ull;
            __syncthreads();
            for (unsigned int e = tid; e < E; e += 512) {
                unsigned int uu = edges[e];
                unsigned int i = uu >> 13, j = uu & 8191u;
                if ((av[i >> 6] >> (i & 63)) & 1ull)
                    atomicOr(&u.r.supp[j >> 6], 1ull << (j & 63));
            }
            if (tid == 0) flag = 0;
            __syncthreads();
            if (tid < 128) {
                unsigned long long na = u.r.vd[tid] & ~u.r.supp[tid];
                if (na != av[tid]) { av[tid] = na; flag = 1; }
            }
            __syncthreads();
            if (!flag) break;
        }
    }

    // ---------------- output (verified 16-chunk dbuf LDS transpose) ----------------
    {
        const float* s0 = (const float*)(ws + SB(0));
        const float* s1 = (const float*)(ws + SB(1));
        const float* s2 = (const float*)(ws + SB(2));
        const float* s3 = (const float*)(ws + SB(3));
        const float* s4 = (const float*)(ws + SB(4));
        const float* s5 = (const float*)(ws + SB(5));

        for (int c = 0; c < 16; ++c) {
            int r = (c << 9) + tid;               // rank 0..8191
            int p = c & 1;
            float v0 = 0.f, v1 = 0.f, v2 = 0.f, v3 = 0.f, v4 = 0.f, v5 = 0.f;
            if ((av[r >> 6] >> (r & 63)) & 1ull) {
                v0 = s0[r]; v1 = s1[r]; v2 = s2[r];
                v3 = s3[r]; v4 = s4[r]; v5 = s5[r];
            }
            u.o.obuf[p][tid * 6 + 0] = v0; u.o.obuf[p][tid * 6 + 1] = v1;
            u.o.obuf[p][tid * 6 + 2] = v2; u.o.obuf[p][tid * 6 + 3] = v3;
            u.o.obuf[p][tid * 6 + 4] = v4; u.o.obuf[p][tid * 6 + 5] = v5;
            __syncthreads();
            int basef = c * 3072;                 // float index of chunk start
            const float4* src = (const float4*)u.o.obuf[p];
            float4* dst = (float4*)(out + basef);
            #pragma unroll
            for (int tq = tid; tq < 768; tq += 512)
                if ((basef >> 2) + tq < (NBOX * 6) / 4) dst[tq] = src[tq];
        }
    }
}

extern "C" void kernel_launch(void* const* d_in, const int* in_sizes, int n_in,
                              void* d_out, int out_size, void* d_ws, size_t ws_size,
                              hipStream_t stream) {
    const float* x       = (const float*)d_in[0];
    const float* anchors = (const float*)d_in[1];
    float* out           = (float*)d_out;
    unsigned char* ws    = (unsigned char*)d_ws;

    sort_decode_kernel<<<256, 512, 0, stream>>>(x, anchors, ws);
    mask_nms_out_kernel<<<256, 512, 0, stream>>>(ws, out);
}

// Round 6
// 141.152 us; speedup vs baseline: 1.4080x; 1.3787x over previous
//
#include <hip/hip_runtime.h>
#include <stdint.h>

#define NBOX 8000
#define NPAD 8192
#define ECAP 6144                            // packed cross-edge LDS capacity

// ---- workspace layout (bytes) ----
#define ECNT_OFF 0                           // u32 edge count (zeroed by K1)
#define DONE_OFF 64                          // u32 finished-block count (zeroed by K1)
#define SB(i)    (0x10000 + (size_t)(i) * 0x8000)
// sorted-by-rank arrays (float[8192] each):
// 0 bx, 1 by, 2 bw, 3 bh, 4 conf, 5 cls, 6 x1, 7 y1, 8 x2, 9 y2, 10 area
#define EDGE_OFF (size_t)0x200000            // flat u32 edges (i<<13|j)

__device__ __forceinline__ float sigmoidf_(float x) {
    return 1.0f / (1.0f + expf(-x));
}

// ================= K1: fused decode-conf + ballot-rank + scatter-to-sorted =================
// (verbatim verified rounds 1-5)
__global__ __launch_bounds__(512) void sort_decode_kernel(const float* __restrict__ x,
                                                          const float* __restrict__ anchors,
                                                          unsigned char* __restrict__ ws) {
    __shared__ unsigned long long keys[NPAD];    // 64 KB
    __shared__ int partial[256];                 // 8 waves x 32 rows
    int tid  = threadIdx.x;
    int lane = tid & 63;
    int wv   = tid >> 6;                         // wave 0..7
    int b    = blockIdx.x;                       // 256 blocks

    if (b == 0 && tid == 0) {
        *(unsigned int*)(ws + ECNT_OFF) = 0u;    // edge count for K2
        *(unsigned int*)(ws + DONE_OFF) = 0u;    // done-block count for K2
    }

    // ---- phase 1: all keys -> LDS (16 coalesced loads/thread) ----
    for (int t = tid; t < NPAD; t += 512) {
        unsigned long long k;
        if (t < NBOX) {
            int a = t / 1600, pos = t - a * 1600;
            float c = sigmoidf_(x[a * 40000 + 4 * 1600 + pos]);
            k = ((unsigned long long)__float_as_uint(c) << 32) | (unsigned long long)(8191 - t);
        } else {
            k = (unsigned long long)(8191 - t);  // pads sort last (conf bits = 0)
        }
        keys[t] = k;
    }
    __syncthreads();

    // ---- phase 2: ballot-rank; wave wv vs segment wv ----
    unsigned long long kj[16];
    #pragma unroll
    for (int c = 0; c < 16; ++c) kj[c] = keys[(wv << 10) + (c << 6) + lane];
    unsigned long long ki = keys[(b << 5) + lane];

    int vout = 0;                                // lane L ends with partial for row L
    for (int ii = 0; ii < 32; ++ii) {
        unsigned int klo = (unsigned int)__builtin_amdgcn_readlane((int)(unsigned int)ki, ii);
        unsigned int khi = (unsigned int)__builtin_amdgcn_readlane((int)(unsigned int)(ki >> 32), ii);
        unsigned long long kib = ((unsigned long long)khi << 32) | (unsigned long long)klo;
        int c = 0;
        #pragma unroll
        for (int ch = 0; ch < 16; ++ch)
            c += __popcll(__ballot(kj[ch] > kib));
        vout = (lane == ii) ? c : vout;
    }
    if (lane < 32) partial[(wv << 5) + lane] = vout;
    __syncthreads();

    // ---- phase 3: wave 0 lanes 0..31 sum partials, decode, scatter-write ----
    if (wv == 0 && lane < 32) {
        int r = 0;
        #pragma unroll
        for (int s = 0; s < 8; ++s) r += partial[(s << 5) + lane];

        int i = (b << 5) + lane;                 // source box owned by this lane
        float bx = 0.f, by = 0.f, bw = 0.f, bh = 0.f, conf = 0.f, cls = -1.0f;
        if (i < NBOX) {                          // full decode (coalesced channel loads)
            int a = i / 1600, pos = i - a * 1600;
            int gy = pos / 40, gx = pos - gy * 40;
            const float* p = x + (size_t)a * 40000 + pos;
            float tx = sigmoidf_(p[0]);
            float ty = sigmoidf_(p[1600]);
            float tw = p[2 * 1600];
            float th = p[3 * 1600];
            conf = sigmoidf_(p[4 * 1600]);
            float best = -1.0f; int bi = 0;
            #pragma unroll
            for (int c = 0; c < 20; ++c) {       // first-max wins, matches jnp.argmax
                float v = sigmoidf_(p[(5 + c) * 1600]);
                if (v > best) { best = v; bi = c; }
            }
            float aw = anchors[a * 2 + 0];
            float ah = anchors[a * 2 + 1];
            bx = (tx + (float)gx) * 8.0f;
            by = (ty + (float)gy) * 8.0f;
            bw = expf(tw) * aw * 8.0f;
            bh = expf(th) * ah * 8.0f;
            cls = (float)bi;
        }
        {
        #pragma clang fp contract(off)
            float x1 = bx - bw / 2.0f, y1 = by - bh / 2.0f;
            float x2 = bx + bw / 2.0f, y2 = by + bh / 2.0f;
            float ar = fabsf((x2 - x1) * (y2 - y1));   // ref: recomputed from corners
            ((float*)(ws + SB(0)))[r]  = bx;  ((float*)(ws + SB(1)))[r]  = by;
            ((float*)(ws + SB(2)))[r]  = bw;  ((float*)(ws + SB(3)))[r]  = bh;
            ((float*)(ws + SB(4)))[r]  = conf; ((float*)(ws + SB(5)))[r] = cls;
            ((float*)(ws + SB(6)))[r]  = x1;  ((float*)(ws + SB(7)))[r]  = y1;
            ((float*)(ws + SB(8)))[r]  = x2;  ((float*)(ws + SB(9)))[r]  = y2;
            ((float*)(ws + SB(10)))[r] = ar;
        }
    }
}

// ================= K2: suppression edges + last-block push-sweep NMS + output =================
// Phase 0: every block pre-zeroes the output rows of its 32 ranks that are
//          invalid (conf<=0.5 / poison) — parallelizes half the output.
// Phase 1: verified tile loop, but the inner 64-col scan is replaced by a
//          per-class column bitmask (20 ballots by the staging wave): each
//          row iterates only same-class/valid/j>i columns (~2 bits vs 64).
//          Edge emission verbatim (wave-aggregated, fire-and-forget).
// Tail (last block): bucket cross edges by I-chunk in LDS, intra edges in a
//          64x64 bit matrix. Then a PUSH-based greedy sweep: finalizing
//          chunk jc pushes its alive rows' out-edges into supp[] of future
//          chunks via parallel LDS atomicOr — per-chunk dependent chain is
//          ~1 LDS read (vs round-5's pull + 64-bit shfl reduce, which was
//          ~1.5k cy/chunk of pure latency = the 139 us regression).
__global__ __launch_bounds__(512) void mask_nms_out_kernel(unsigned char* __restrict__ ws,
                                                           float* __restrict__ out) {
    __shared__ unsigned long long av[128];                // final alive bits
    __shared__ union {
        struct { float cst[2][7][64];
                 unsigned long long cm[2][20], vm[2]; } m;   // mask staging + class masks
        struct { unsigned int bcnt[128], offs[128], cur[128], cntL[128];
                 unsigned long long vd[128], supp[128], nzm[128];
                 unsigned int eLDS[ECAP];                 // 24 KB
                 unsigned long long intra[128 * 64]; } r; // 64 KB  => ~93 KB total
        struct { float obuf[2][3072]; } o;                // 24 KB output staging
    } u;
    __shared__ int lastBlk, flag;

    int tid  = threadIdx.x;
    int lane = tid & 63;
    int wv   = tid >> 6;
    int blk  = blockIdx.x;                                // 256 blocks

    const float* sconf = (const float*)(ws + SB(4));
    const float* sx1 = (const float*)(ws + SB(6));
    const float* sy1 = (const float*)(ws + SB(7));
    const float* sx2 = (const float*)(ws + SB(8));
    const float* sy2 = (const float*)(ws + SB(9));
    const float* sar = (const float*)(ws + SB(10));
    const float* scl = (const float*)(ws + SB(5));

    // ---------------- phase 0: pre-zero invalid-rank output rows ----------------
    if (tid < 192) {
        int r = (blk << 5) + tid / 6;
        if (r < NBOX && !(sconf[r] > 0.5f))               // NaN/poison-safe negated test
            out[r * 6 + tid % 6] = 0.0f;
    }

    // ---------------- phase 1: suppression-edge tiles (class-bitmask inner loop) ----------------
    {
    #pragma clang fp contract(off)
        int h  = tid >> 8;                       // half-block 0/1 (4 waves each)
        int tl = tid & 255;

        for (int k = 0; k < 8; ++k) {
            int t  = k * 512 + (blk << 1) + h;   // tile id in [0, 4096)
            int iy = t >> 7, w = t & 127;
            int i0 = iy << 8, j0 = w << 6;
            bool skip = (sconf[i0] <= 0.5f) || (sconf[j0] <= 0.5f) || (j0 + 64 <= i0);

            if (!skip && tl < 64) {              // full wave: stage cols + build masks
                int j = j0 + tl;
                float c0 = sx1[j], c1 = sy1[j], c2 = sx2[j], c3 = sy2[j];
                float c4 = sar[j], c5 = scl[j], c6 = sconf[j];
                u.m.cst[h][0][tl] = c0; u.m.cst[h][1][tl] = c1;
                u.m.cst[h][2][tl] = c2; u.m.cst[h][3][tl] = c3;
                u.m.cst[h][4][tl] = c4; u.m.cst[h][5][tl] = c5;
                u.m.cst[h][6][tl] = c6;
                unsigned long long vmk = __ballot(c6 > 0.5f);      // == !(c6<=0.5), NaN-safe
                if (tl == 0) u.m.vm[h] = vmk;
                #pragma unroll
                for (int cl = 0; cl < 20; ++cl) {
                    unsigned long long mk = __ballot(c5 == (float)cl);  // == !(ccl!=ci)
                    if (tl == 0) u.m.cm[h][cl] = mk;
                }
            }
            __syncthreads();

            if (!skip) {
                int i = i0 + tl;
                unsigned long long word = 0;
                if (sconf[i] > 0.5f && j0 + 64 > i + 1) {  // row i valid
                    float x1i = sx1[i], y1i = sy1[i], x2i = sx2[i], y2i = sy2[i];
                    float ai = sar[i], ci = scl[i];
                    int cii = (int)ci;
                    unsigned long long allowed = 0ull;
                    if (cii >= 0 && cii < 20)
                        allowed = u.m.cm[h][cii] & u.m.vm[h];
                    int d = i - j0 + 1;                    // first allowed col: j>i
                    unsigned long long gt =
                        (d <= 0) ? ~0ull : (d >= 64 ? 0ull : (~0ull << d));
                    unsigned long long it = allowed & gt;
                    while (it) {
                        int jj = __builtin_ctzll(it);
                        it &= it - 1ull;
                        float iw = fminf(x2i, u.m.cst[h][2][jj]) - fmaxf(x1i, u.m.cst[h][0][jj]);
                        iw = fmaxf(iw, 0.0f);
                        float ih = fminf(y2i, u.m.cst[h][3][jj]) - fmaxf(y1i, u.m.cst[h][1][jj]);
                        ih = fmaxf(ih, 0.0f);
                        float inter = iw * ih;
                        float denom = ai + u.m.cst[h][4][jj] - inter + 1e-6f;
                        if (inter / denom >= 0.5f) word |= (1ull << jj);
                    }
                }
                // wave-aggregated edge emission (verbatim verified)
                int pc = __popcll(word);
                int scan = pc;
                #pragma unroll
                for (int d = 1; d < 64; d <<= 1) {
                    int tt = __shfl_up(scan, d, 64);
                    if (lane >= d) scan += tt;
                }
                int total = __shfl(scan, 63, 64);
                if (total > 0) {
                    unsigned int base = 0;
                    if (lane == 63)
                        base = atomicAdd((unsigned int*)(ws + ECNT_OFF), (unsigned int)total);
                    base = (unsigned int)__shfl((int)base, 63, 64);
                    unsigned int off = base + (unsigned int)(scan - pc);   // exclusive prefix
                    unsigned int* edges = (unsigned int*)(ws + EDGE_OFF);
                    unsigned long long tw = word;
                    while (tw) {
                        int bit = __builtin_ctzll(tw);
                        tw &= tw - 1ull;
                        edges[off++] = ((unsigned int)i << 13) | (unsigned int)(j0 + bit);
                    }
                }
            }
            __syncthreads();
        }
    }

    // ---------------- completion detection: last block continues ----------------
    __threadfence();                              // release this block's edge writes
    if (tid == 0)
        lastBlk = (atomicAdd((unsigned int*)(ws + DONE_OFF), 1u) == 255u);
    __syncthreads();
    if (!lastBlk) return;
    __threadfence();                              // acquire: see all blocks' edges

    unsigned int E = *(const unsigned int*)(ws + ECNT_OFF);
    const unsigned int* edges = (const unsigned int*)(ws + EDGE_OFF);

    // ---------------- tail step 1: valid bitmap + zero LDS state ----------------
    for (int c = wv; c < 128; c += 8) {
        unsigned long long mk = __ballot(sconf[(c << 6) + lane] > 0.5f);
        if (lane == 0) u.r.vd[c] = mk;
    }
    for (int t = tid; t < 128 * 64; t += 512) u.r.intra[t] = 0ull;
    if (tid < 128) {
        u.r.bcnt[tid] = 0u; u.r.supp[tid] = 0ull; u.r.nzm[tid] = 0ull; av[tid] = 0ull;
    }
    __syncthreads();

    if (E <= (unsigned int)ECAP) {
        // ---- pass 1: classify edges by I-chunk; count cross, OR intra bits ----
        for (unsigned int e = tid; e < E; e += 512) {
            unsigned int uu = edges[e];
            unsigned int i = uu >> 13, j = uu & 8191u;
            unsigned int ic = i >> 6;
            if ((j >> 6) == ic) {
                atomicOr(&u.r.intra[(ic << 6) + (i & 63)], 1ull << (j & 63));
                atomicOr(&u.r.nzm[ic], 1ull << (i & 63));
            } else {
                atomicAdd(&u.r.bcnt[ic], 1u);
            }
        }
        __syncthreads();
        // ---- exclusive prefix over 128 bucket counts (wave 0, verified pattern) ----
        if (wv == 0) {
            unsigned int a0 = u.r.bcnt[2 * lane + 0];
            unsigned int a1 = u.r.bcnt[2 * lane + 1];
            unsigned int s = a0 + a1, incl = s;
            #pragma unroll
            for (int d = 1; d < 64; d <<= 1) {
                unsigned int t = __shfl_up(incl, d, 64);
                if (lane >= d) incl += t;
            }
            unsigned int excl = incl - s;
            u.r.offs[2 * lane + 0] = excl;       u.r.offs[2 * lane + 1] = excl + a0;
            u.r.cur[2 * lane + 0]  = excl;       u.r.cur[2 * lane + 1]  = excl + a0;
            u.r.cntL[2 * lane + 0] = a0;         u.r.cntL[2 * lane + 1] = a1;
        }
        __syncthreads();
        // ---- pass 2: scatter cross edges into packed per-i-chunk lists ----
        for (unsigned int e = tid; e < E; e += 512) {
            unsigned int uu = edges[e];
            unsigned int i = uu >> 13, j = uu & 8191u;
            unsigned int ic = i >> 6;
            if ((j >> 6) != ic) {
                unsigned int idx = atomicAdd(&u.r.cur[ic], 1u);
                u.r.eLDS[idx] = uu;
            }
        }
        __syncthreads();
        // ---- push-based greedy sweep (wave 0): chunk jc finalizes, pushes out-edges ----
        if (wv == 0) {
            for (int jc = 0; jc < 128; ++jc) {
                unsigned long long v = u.r.vd[jc];
                if (v == 0ull) continue;          // no valid rows: av stays 0, no pushes
                unsigned long long a = v & ~u.r.supp[jc];
                // intra-chunk: ascending scan over rows with intra edges (bits j>i only)
                unsigned long long nzc = u.r.nzm[jc] & a;
                while (nzc) {
                    int ib = __builtin_ctzll(nzc);
                    nzc &= nzc - 1ull;
                    if ((a >> ib) & 1ull) a &= ~u.r.intra[(jc << 6) + ib];
                }
                if (lane == 0) av[jc] = a;
                // push cross edges of surviving rows into future chunks' supp
                unsigned int cnt = u.r.cntL[jc], off = u.r.offs[jc];
                for (unsigned int e0 = 0; e0 < cnt; e0 += 64) {
                    unsigned int e = e0 + lane;
                    if (e < cnt) {
                        unsigned int uu = u.r.eLDS[off + e];
                        unsigned int i = uu >> 13, j = uu & 8191u;
                        if ((a >> (i & 63)) & 1ull)
                            atomicOr(&u.r.supp[j >> 6], 1ull << (j & 63));
                    }
                }
                asm volatile("s_waitcnt lgkmcnt(0)" ::: "memory");  // pushes before next supp read
                __builtin_amdgcn_sched_barrier(0);
            }
        }
        __syncthreads();
    } else {
        // ---- fallback: Jacobi fixed point on global edges (verified; E>ECAP only) ----
        if (tid < 128) av[tid] = u.r.vd[tid];
        __syncthreads();
        for (;;) {
            if (tid < 128) u.r.supp[tid] = 0ull;
            __syncthreads();
            for (unsigned int e = tid; e < E; e += 512) {
                unsigned int uu = edges[e];
                unsigned int i = uu >> 13, j = uu & 8191u;
                if ((av[i >> 6] >> (i & 63)) & 1ull)
                    atomicOr(&u.r.supp[j >> 6], 1ull << (j & 63));
            }
            if (tid == 0) flag = 0;
            __syncthreads();
            if (tid < 128) {
                unsigned long long na = u.r.vd[tid] & ~u.r.supp[tid];
                if (na != av[tid]) { av[tid] = na; flag = 1; }
            }
            __syncthreads();
            if (!flag) break;
        }
    }

    // ---------------- output: only chunks containing valid ranks (rest pre-zeroed) ----------------
    {
        const float* s0 = (const float*)(ws + SB(0));
        const float* s1 = (const float*)(ws + SB(1));
        const float* s2 = (const float*)(ws + SB(2));
        const float* s3 = (const float*)(ws + SB(3));
        const float* s4 = (const float*)(ws + SB(4));
        const float* s5 = (const float*)(ws + SB(5));

        for (int c = 0; c < 16; ++c) {
            if (!(sconf[c << 9] > 0.5f)) continue;   // sorted: chunk fully invalid (uniform)
            int r = (c << 9) + tid;               // rank 0..8191
            int p = c & 1;
            float v0 = 0.f, v1 = 0.f, v2 = 0.f, v3 = 0.f, v4 = 0.f, v5 = 0.f;
            if ((av[r >> 6] >> (r & 63)) & 1ull) {
                v0 = s0[r]; v1 = s1[r]; v2 = s2[r];
                v3 = s3[r]; v4 = s4[r]; v5 = s5[r];
            }
            u.o.obuf[p][tid * 6 + 0] = v0; u.o.obuf[p][tid * 6 + 1] = v1;
            u.o.obuf[p][tid * 6 + 2] = v2; u.o.obuf[p][tid * 6 + 3] = v3;
            u.o.obuf[p][tid * 6 + 4] = v4; u.o.obuf[p][tid * 6 + 5] = v5;
            __syncthreads();
            int basef = c * 3072;                 // float index of chunk start
            const float4* src = (const float4*)u.o.obuf[p];
            float4* dst = (float4*)(out + basef);
            #pragma unroll
            for (int tq = tid; tq < 768; tq += 512)
                if ((basef >> 2) + tq < (NBOX * 6) / 4) dst[tq] = src[tq];
        }
    }
}

extern "C" void kernel_launch(void* const* d_in, const int* in_sizes, int n_in,
                              void* d_out, int out_size, void* d_ws, size_t ws_size,
                              hipStream_t stream) {
    const float* x       = (const float*)d_in[0];
    const float* anchors = (const float*)d_in[1];
    float* out           = (float*)d_out;
    unsigned char* ws    = (unsigned char*)d_ws;

    sort_decode_kernel<<<256, 512, 0, stream>>>(x, anchors, ws);
    mask_nms_out_kernel<<<256, 512, 0, stream>>>(ws, out);
}